// Round 7
// baseline (57.378 us; speedup 1.0000x reference)
//
#include <hip/hip_runtime.h>
#include <math.h>

#define TOPM 2048   // top-M node ids served by the dense GEMM table

typedef _Float16 f16x8 __attribute__((ext_vector_type(8)));
typedef float    f32x4 __attribute__((ext_vector_type(4)));

// ---- DPP wave reductions: VALU pipe only ----
template<int CTRL, int ROW_MASK>
__device__ __forceinline__ float dpp_add(float v) {
    const int s = __builtin_amdgcn_update_dpp(0, __float_as_int(v), CTRL, ROW_MASK, 0xf, false);
    return v + __int_as_float(s);
}
template<int CTRL, int ROW_MASK>
__device__ __forceinline__ float dpp_mul(float v) {
    const int s = __builtin_amdgcn_update_dpp(0x3f800000, __float_as_int(v), CTRL, ROW_MASK, 0xf, false);
    return v * __int_as_float(s);
}
__device__ __forceinline__ float wave_sum63(float v) {   // total in lane 63
    v = dpp_add<0x111, 0xf>(v); v = dpp_add<0x112, 0xf>(v); v = dpp_add<0x114, 0xf>(v);
    v = dpp_add<0x118, 0xf>(v); v = dpp_add<0x142, 0xa>(v); v = dpp_add<0x143, 0xc>(v);
    return v;
}
__device__ __forceinline__ float wave_prod63(float v) {  // product in lane 63
    v = dpp_mul<0x111, 0xf>(v); v = dpp_mul<0x112, 0xf>(v); v = dpp_mul<0x114, 0xf>(v);
    v = dpp_mul<0x118, 0xf>(v); v = dpp_mul<0x142, 0xa>(v); v = dpp_mul<0x143, 0xc>(v);
    return v;
}
__device__ __forceinline__ float readlane_f(float v, int l) {
    return __int_as_float(__builtin_amdgcn_readlane(__float_as_int(v), l));
}
__device__ __forceinline__ float dot8(float4 a, float4 b, float4 c, float4 d) {
    return a.x*b.x + a.y*b.y + a.z*b.z + a.w*b.w + c.x*d.x + c.y*d.y + c.z*d.z + c.w*d.w;
}
__device__ __forceinline__ f16x8 pack8(float4 f0, float4 f1) {
    f16x8 h;
    h[0]=(_Float16)f0.x; h[1]=(_Float16)f0.y; h[2]=(_Float16)f0.z; h[3]=(_Float16)f0.w;
    h[4]=(_Float16)f1.x; h[5]=(_Float16)f1.y; h[6]=(_Float16)f1.z; h[7]=(_Float16)f1.w;
    return h;
}

// Kernel 1: Y[b][j] = x[b] . W[tb+j] + bias[tb+j], j in [0,TOPM), via fp16 MFMA.
// Block = 4 waves = 64(m=node) x 64(n=batch) tile; wave w owns 16 m-rows.
// Fragment k-mapping: k = 8*(lane>>4)+i for BOTH A and B (any consistent
// bijection is correct — hardware pairs same (group,slot) regardless of k).
// C/D: col=lane&15 (n), row=(lane>>4)*4+reg (m)  [m89-verified, dtype-indep].
__global__ __launch_bounds__(256)
void dense_top_gemm(const float* __restrict__ x, const float* __restrict__ W,
                    const float* __restrict__ bias, float* __restrict__ Y,
                    int N, int B)
{
    const int lane = threadIdx.x & 63;
    const int w    = threadIdx.x >> 6;
    const int mt   = blockIdx.x % (TOPM / 64);
    const int nt   = blockIdx.x / (TOPM / 64);
    const int tb   = N - TOPM;
    const int g    = lane >> 4;
    const int l15  = lane & 15;

    const float* arow = W + (size_t)(tb + mt*64 + w*16 + l15) * 512;
    const float* brow0 = x + (size_t)(nt*64 +  0 + l15) * 512;
    const float* brow1 = x + (size_t)(nt*64 + 16 + l15) * 512;
    const float* brow2 = x + (size_t)(nt*64 + 32 + l15) * 512;
    const float* brow3 = x + (size_t)(nt*64 + 48 + l15) * 512;

    f32x4 acc0 = {0,0,0,0}, acc1 = {0,0,0,0}, acc2 = {0,0,0,0}, acc3 = {0,0,0,0};

    #pragma unroll 4
    for (int k0 = 0; k0 < 512; k0 += 32) {
        const int ko = k0 + 8*g;
        const f16x8 a = pack8(*(const float4*)(arow + ko), *(const float4*)(arow + ko + 4));
        const f16x8 b0 = pack8(*(const float4*)(brow0 + ko), *(const float4*)(brow0 + ko + 4));
        const f16x8 b1 = pack8(*(const float4*)(brow1 + ko), *(const float4*)(brow1 + ko + 4));
        const f16x8 b2 = pack8(*(const float4*)(brow2 + ko), *(const float4*)(brow2 + ko + 4));
        const f16x8 b3 = pack8(*(const float4*)(brow3 + ko), *(const float4*)(brow3 + ko + 4));
        acc0 = __builtin_amdgcn_mfma_f32_16x16x32_f16(a, b0, acc0, 0, 0, 0);
        acc1 = __builtin_amdgcn_mfma_f32_16x16x32_f16(a, b1, acc1, 0, 0, 0);
        acc2 = __builtin_amdgcn_mfma_f32_16x16x32_f16(a, b2, acc2, 0, 0, 0);
        acc3 = __builtin_amdgcn_mfma_f32_16x16x32_f16(a, b3, acc3, 0, 0, 0);
    }

    const int jn = mt*64 + w*16 + g*4;     // node index of reg 0
    float bb[4];
    #pragma unroll
    for (int r = 0; r < 4; ++r) bb[r] = bias[tb + jn + r];
    #pragma unroll
    for (int r = 0; r < 4; ++r) {
        Y[(size_t)(nt*64 +  0 + l15) * TOPM + jn + r] = acc0[r] + bb[r];
        Y[(size_t)(nt*64 + 16 + l15) * TOPM + jn + r] = acc1[r] + bb[r];
        Y[(size_t)(nt*64 + 32 + l15) * TOPM + jn + r] = acc2[r] + bb[r];
        Y[(size_t)(nt*64 + 48 + l15) * TOPM + jn + r] = acc3[r] + bb[r];
    }
}

// Kernel 2: wave per (b,r) pair. Table-prefix (node id >= tb) served from Y;
// suffix (up to 6 entries) gathered with batched loads. Gather is correct for
// ANY node id, so boundary-level id mixing is safe.
__global__ __launch_bounds__(256)
void huff_combine(const float* __restrict__ x, const int* __restrict__ tgt,
                  const float* __restrict__ W, const float* __restrict__ bias,
                  const int* __restrict__ paths, const float* __restrict__ codes,
                  const float* __restrict__ Y, float* __restrict__ out,
                  int R, int N)
{
    const int lane = threadIdx.x & 63;
    const int p = blockIdx.x * 4 + (threadIdx.x >> 6);
    const int b = p / R;
    const int tb = N - TOPM;

    const float4* xr = reinterpret_cast<const float4*>(x + (size_t)b * 512);
    const float4 xa = xr[lane], xb = xr[lane + 64];

    const int c  = tgt[p];
    const int dd = (lane < 16) ? lane : 15;
    const int   nd = paths[(size_t)c * 16 + dd];
    const float cd = codes[(size_t)c * 16 + dd];
    const float sd = 1.0f - 2.0f * cd;
    const float bv = bias[nd];

    const unsigned long long mask = __ballot(lane < 16 && nd >= tb);
    const int L = (int)__builtin_ctzll(~mask | (1ull << 16));  // table prefix len

    if (L >= 10) {
        // prefix factors from the table (Y already includes bias)
        float f = 1.0f;
        if (lane < L) {
            const float t = Y[(size_t)b * TOPM + (nd - tb)];
            f = 1.0f + __expf(-sd * t);
        }
        f = wave_prod63(f);
        float q = readlane_f(f, 63);

        // suffix: up to 6 gathered rows, all loads batched for MLP
        float4 wA[6], wB[6];
        #pragma unroll
        for (int s = 0; s < 6; ++s) {
            const int d = (L + s < 16) ? (L + s) : 15;
            const int nid = __builtin_amdgcn_readlane(nd, d);
            const float4* wr = reinterpret_cast<const float4*>(W + (size_t)nid * 512);
            wA[s] = wr[lane]; wB[s] = wr[lane + 64];
        }
        float accs[6];
        #pragma unroll
        for (int s = 0; s < 6; ++s) accs[s] = dot8(xa, wA[s], xb, wB[s]);
        #pragma unroll
        for (int s = 0; s < 6; ++s) accs[s] = wave_sum63(accs[s]);
        #pragma unroll
        for (int s = 0; s < 6; ++s) {
            if (L + s < 16) {
                const float tot = readlane_f(accs[s], 63) + readlane_f(bv, L + s);
                const float ss  = readlane_f(sd, L + s);
                q *= 1.0f + __expf(-ss * tot);
            }
        }
        if (lane == 0) out[p] = 1.0f / q;
    } else {
        // general slow path (not expected): serial per-entry, table or gather
        float q = 1.0f;
        for (int d = 0; d < 16; ++d) {
            const int nid = __builtin_amdgcn_readlane(nd, d);
            const float ss = readlane_f(sd, d);
            float t;
            if (nid >= tb) {
                t = Y[(size_t)b * TOPM + (nid - tb)];
            } else {
                const float4* wr = reinterpret_cast<const float4*>(W + (size_t)nid * 512);
                float a = dot8(xa, wr[lane], xb, wr[lane + 64]);
                a = wave_sum63(a);
                t = readlane_f(a, 63) + readlane_f(bv, d);
            }
            q *= 1.0f + __expf(-ss * t);
        }
        if (lane == 0) out[p] = 1.0f / q;
    }
}

// Generic fallback for unexpected shapes.
__global__ __launch_bounds__(256)
void huff_kernel_gen(const float* __restrict__ x, const int* __restrict__ tgt,
                     const float* __restrict__ W, const float* __restrict__ bias,
                     const int* __restrict__ paths, const float* __restrict__ codes,
                     float* __restrict__ out, int R, int I, int D, int npairs)
{
    const int lane = threadIdx.x & 63;
    const int p = blockIdx.x * 4 + (threadIdx.x >> 6);
    if (p >= npairs) return;
    const int b = p / R;
    const float4* xrow = reinterpret_cast<const float4*>(x + (size_t)b * I);
    const float4 xa = xrow[lane];
    const float4 xb = xrow[lane + 64];
    const int c = tgt[p];
    float q = 1.0f;
    for (int d = 0; d < D; ++d) {
        const int node = paths[(size_t)c * D + d];
        const float4* wr = reinterpret_cast<const float4*>(W + (size_t)node * I);
        float acc = dot8(xa, wr[lane], xb, wr[lane + 64]);
        #pragma unroll
        for (int off = 32; off; off >>= 1) acc += __shfl_xor(acc, off, 64);
        const float t = acc + bias[node];
        const float s = 1.0f - 2.0f * codes[(size_t)c * D + d];
        q *= 1.0f + __expf(-s * t);
    }
    if (lane == 0) out[p] = 1.0f / q;
}

extern "C" void kernel_launch(void* const* d_in, const int* in_sizes, int n_in,
                              void* d_out, int out_size, void* d_ws, size_t ws_size,
                              hipStream_t stream) {
    const float* x     = (const float*)d_in[0];
    const int*   tgt   = (const int*)  d_in[1];
    const float* W     = (const float*)d_in[2];
    const float* bias  = (const float*)d_in[3];
    const int*   paths = (const int*)  d_in[4];
    const float* codes = (const float*)d_in[5];
    float* out = (float*)d_out;

    const int N = in_sizes[3];            // total_nodes = nb_classes - 1
    const int C = N + 1;                  // nb_classes
    const int I = in_sizes[2] / N;        // input dim (512)
    const int B = in_sizes[0] / I;        // batch (1024)
    const int R = in_sizes[1] / B;        // requests (8)
    const int D = in_sizes[4] / C;        // max path depth

    const int npairs = B * R;
    const size_t ws_need = (size_t)B * TOPM * sizeof(float);

    if (D == 16 && I == 512 && (B % 64) == 0 && (npairs % 4) == 0 &&
        N > TOPM + 64 && ws_size >= ws_need) {
        float* Y = (float*)d_ws;
        dense_top_gemm<<<(TOPM / 64) * (B / 64), 256, 0, stream>>>(x, W, bias, Y, N, B);
        huff_combine<<<npairs / 4, 256, 0, stream>>>(x, tgt, W, bias, paths, codes,
                                                     Y, out, R, N);
    } else {
        const int grid = (npairs + 3) / 4;
        huff_kernel_gen<<<grid, 256, 0, stream>>>(x, tgt, W, bias, paths, codes,
                                                  out, R, I, D, npairs);
    }
}

// Round 8
// 34.610 us; speedup vs baseline: 1.6578x; 1.6578x over previous
//
#include <hip/hip_runtime.h>
#include <math.h>

#define TOPM 2048   // top-M node ids served by the dense GEMM table

typedef _Float16 f16x8 __attribute__((ext_vector_type(8)));
typedef _Float16 f16x4 __attribute__((ext_vector_type(4)));
typedef float    f32x4 __attribute__((ext_vector_type(4)));

// ---- DPP wave reductions: VALU pipe only ----
template<int CTRL, int ROW_MASK>
__device__ __forceinline__ float dpp_add(float v) {
    const int s = __builtin_amdgcn_update_dpp(0, __float_as_int(v), CTRL, ROW_MASK, 0xf, false);
    return v + __int_as_float(s);
}
template<int CTRL, int ROW_MASK>
__device__ __forceinline__ float dpp_mul(float v) {
    const int s = __builtin_amdgcn_update_dpp(0x3f800000, __float_as_int(v), CTRL, ROW_MASK, 0xf, false);
    return v * __int_as_float(s);
}
__device__ __forceinline__ float wave_sum63(float v) {   // total in lane 63
    v = dpp_add<0x111, 0xf>(v); v = dpp_add<0x112, 0xf>(v); v = dpp_add<0x114, 0xf>(v);
    v = dpp_add<0x118, 0xf>(v); v = dpp_add<0x142, 0xa>(v); v = dpp_add<0x143, 0xc>(v);
    return v;
}
__device__ __forceinline__ float wave_prod63(float v) {  // product in lane 63
    v = dpp_mul<0x111, 0xf>(v); v = dpp_mul<0x112, 0xf>(v); v = dpp_mul<0x114, 0xf>(v);
    v = dpp_mul<0x118, 0xf>(v); v = dpp_mul<0x142, 0xa>(v); v = dpp_mul<0x143, 0xc>(v);
    return v;
}
__device__ __forceinline__ float readlane_f(float v, int l) {
    return __int_as_float(__builtin_amdgcn_readlane(__float_as_int(v), l));
}
__device__ __forceinline__ float dot8(float4 a, float4 b, float4 c, float4 d) {
    return a.x*b.x + a.y*b.y + a.z*b.z + a.w*b.w + c.x*d.x + c.y*d.y + c.z*d.z + c.w*d.w;
}
__device__ __forceinline__ void gld16(const void* g, void* l) {
    __builtin_amdgcn_global_load_lds((const __attribute__((address_space(1))) void*)g,
                                     (__attribute__((address_space(3))) void*)l, 16, 0, 0);
}

// K0: convert W-top (TOPM x 512) and x (B x 512) fp32 -> fp16 into workspace.
__global__ __launch_bounds__(256)
void conv_f16(const float* __restrict__ wsrc, const float* __restrict__ xsrc,
              _Float16* __restrict__ Wh, _Float16* __restrict__ xh,
              int n0, int ntot)
{
    const int i = blockIdx.x * 256 + threadIdx.x;
    if (i >= ntot) return;
    const float4 v = (i < n0) ? reinterpret_cast<const float4*>(wsrc)[i]
                              : reinterpret_cast<const float4*>(xsrc)[i - n0];
    f16x4 h; h[0] = (_Float16)v.x; h[1] = (_Float16)v.y; h[2] = (_Float16)v.z; h[3] = (_Float16)v.w;
    if (i < n0) reinterpret_cast<f16x4*>(Wh)[i] = h;
    else        reinterpret_cast<f16x4*>(xh)[i - n0] = h;
}

// K1: Y[m][n] = sum_k Wh[m][k] * xh[n][k]   (m in [0,TOPM), n in [0,B))
// m97-lite: BM=128, BN=64, BK=64; global_load_lds width-16 staging with
// both-sides XOR swizzle (store src col ((f&7)^(row&7))*8 at linear dest;
// read at cb ^ ((row&7)<<4)) -> conflict-free ds_read_b128.
// MFMA 16x16x32_f16; A/B k-map identical bijection (kk*32+(l>>4)*8+j).
// C/D: col=lane&15 (n), row=(lane>>4)*4+reg (m)  [m89-verified].
__global__ __launch_bounds__(256)
void top_gemm(const _Float16* __restrict__ Wh, const _Float16* __restrict__ xh,
              float* __restrict__ Y, int B)
{
    __shared__ __align__(16) _Float16 At[128 * 64];  // 16 KB
    __shared__ __align__(16) _Float16 Bt[64 * 64];   // 8 KB

    const int tid  = threadIdx.x;
    const int lane = tid & 63;
    const int w    = tid >> 6;
    const int bm   = (blockIdx.x & (TOPM / 128 - 1)) * 128;
    const int bn   = (blockIdx.x / (TOPM / 128)) * 64;
    const int wr   = w & 1;      // wave computes 64x32 at (wr*64, wc*32)
    const int wc   = w >> 1;
    const int l15  = lane & 15;
    const int g    = lane >> 4;

    f32x4 acc[4][2] = {};

    for (int k0 = 0; k0 < 512; k0 += 64) {
        #pragma unroll
        for (int i = 0; i < 4; ++i) {   // A tile: 128x64 f16
            const int f = i * 256 + tid;
            const int row = f >> 3;
            const int scol = ((f & 7) ^ (row & 7)) * 8;
            gld16(Wh + (size_t)(bm + row) * 512 + k0 + scol,
                  (char*)At + (i * 256 + w * 64) * 16);
        }
        #pragma unroll
        for (int i = 0; i < 2; ++i) {   // B tile: 64x64 f16
            const int f = i * 256 + tid;
            const int row = f >> 3;
            const int scol = ((f & 7) ^ (row & 7)) * 8;
            gld16(xh + (size_t)(bn + row) * 512 + k0 + scol,
                  (char*)Bt + (i * 256 + w * 64) * 16);
        }
        asm volatile("s_waitcnt vmcnt(0)" ::: "memory");
        __syncthreads();

        #pragma unroll
        for (int kk = 0; kk < 2; ++kk) {
            f16x8 af[4], bf[2];
            #pragma unroll
            for (int mi = 0; mi < 4; ++mi) {
                const int row = wr * 64 + mi * 16 + l15;
                const int cb = ((kk * 32 + g * 8) * 2) ^ ((row & 7) << 4);
                af[mi] = *reinterpret_cast<const f16x8*>((const char*)At + row * 128 + cb);
            }
            #pragma unroll
            for (int ni = 0; ni < 2; ++ni) {
                const int row = wc * 32 + ni * 16 + l15;
                const int cb = ((kk * 32 + g * 8) * 2) ^ ((row & 7) << 4);
                bf[ni] = *reinterpret_cast<const f16x8*>((const char*)Bt + row * 128 + cb);
            }
            #pragma unroll
            for (int mi = 0; mi < 4; ++mi)
                #pragma unroll
                for (int ni = 0; ni < 2; ++ni)
                    acc[mi][ni] = __builtin_amdgcn_mfma_f32_16x16x32_f16(af[mi], bf[ni], acc[mi][ni], 0, 0, 0);
        }
        __syncthreads();
    }

    #pragma unroll
    for (int mi = 0; mi < 4; ++mi)
        #pragma unroll
        for (int ni = 0; ni < 2; ++ni)
            #pragma unroll
            for (int r = 0; r < 4; ++r) {
                const int m = bm + wr * 64 + mi * 16 + g * 4 + r;
                const int n = bn + wc * 32 + ni * 16 + l15;
                Y[(size_t)m * B + n] = acc[mi][ni][r];
            }
}

// K2: wave per (b,r) pair. Entries with node id >= tb from table Y (bias added
// here); the rest gathered via compact ballot-driven batch (any distribution).
__global__ __launch_bounds__(256)
void huff_combine(const float* __restrict__ x, const int* __restrict__ tgt,
                  const float* __restrict__ W, const float* __restrict__ bias,
                  const int* __restrict__ paths, const float* __restrict__ codes,
                  const float* __restrict__ Y, float* __restrict__ out,
                  int R, int N, int B)
{
    const int lane = threadIdx.x & 63;
    const int p = blockIdx.x * 4 + (threadIdx.x >> 6);
    const int b = p / R;
    const int tb = N - TOPM;

    const float4* xr = reinterpret_cast<const float4*>(x + (size_t)b * 512);
    const float4 xa = xr[lane], xb = xr[lane + 64];

    const int c  = tgt[p];
    const int dd = (lane < 16) ? lane : 15;
    const int   nd = paths[(size_t)c * 16 + dd];
    const float cd = codes[(size_t)c * 16 + dd];
    const float sd = 1.0f - 2.0f * cd;
    const float bv = bias[nd];

    // table-served factors
    float f = 1.0f;
    if (lane < 16 && nd >= tb)
        f = 1.0f + __expf(-sd * (Y[(size_t)(nd - tb) * B + b] + bv));
    f = wave_prod63(f);
    float q = readlane_f(f, 63);

    // gather-needed entries (wave-uniform mask)
    unsigned mm = (unsigned)(__ballot(lane < 16 && nd < tb) & 0xFFFFull);
    int dl[6];
    #pragma unroll
    for (int s = 0; s < 6; ++s) {
        dl[s] = mm ? (int)__builtin_ctz(mm) : -1;
        if (mm) mm &= mm - 1;
    }

    float4 wA[6], wB[6];
    #pragma unroll
    for (int s = 0; s < 6; ++s)
        if (dl[s] >= 0) {
            const int nid = __builtin_amdgcn_readlane(nd, dl[s]);
            const float4* wr = reinterpret_cast<const float4*>(W + (size_t)nid * 512);
            wA[s] = wr[lane]; wB[s] = wr[lane + 64];
        }
    float a6[6];
    #pragma unroll
    for (int s = 0; s < 6; ++s)
        a6[s] = (dl[s] >= 0) ? dot8(xa, wA[s], xb, wB[s]) : 0.0f;
    #pragma unroll
    for (int s = 0; s < 6; ++s)
        if (dl[s] >= 0) a6[s] = wave_sum63(a6[s]);
    #pragma unroll
    for (int s = 0; s < 6; ++s)
        if (dl[s] >= 0) {
            const float tot = readlane_f(a6[s], 63) + readlane_f(bv, dl[s]);
            q *= 1.0f + __expf(-readlane_f(sd, dl[s]) * tot);
        }

    // remainder (rare: >6 gathered entries per path)
    while (mm) {
        const int d = (int)__builtin_ctz(mm); mm &= mm - 1;
        const int nid = __builtin_amdgcn_readlane(nd, d);
        const float4* wr = reinterpret_cast<const float4*>(W + (size_t)nid * 512);
        float a = dot8(xa, wr[lane], xb, wr[lane + 64]);
        a = wave_sum63(a);
        q *= 1.0f + __expf(-readlane_f(sd, d) * (readlane_f(a, 63) + readlane_f(bv, d)));
    }

    if (lane == 0) out[p] = 1.0f / q;
}

// Generic fallback for unexpected shapes.
__global__ __launch_bounds__(256)
void huff_kernel_gen(const float* __restrict__ x, const int* __restrict__ tgt,
                     const float* __restrict__ W, const float* __restrict__ bias,
                     const int* __restrict__ paths, const float* __restrict__ codes,
                     float* __restrict__ out, int R, int I, int D, int npairs)
{
    const int lane = threadIdx.x & 63;
    const int p = blockIdx.x * 4 + (threadIdx.x >> 6);
    if (p >= npairs) return;
    const int b = p / R;
    const float4* xrow = reinterpret_cast<const float4*>(x + (size_t)b * I);
    const float4 xa = xrow[lane];
    const float4 xb = xrow[lane + 64];
    const int c = tgt[p];
    float q = 1.0f;
    for (int d = 0; d < D; ++d) {
        const int node = paths[(size_t)c * D + d];
        const float4* wr = reinterpret_cast<const float4*>(W + (size_t)node * I);
        float acc = dot8(xa, wr[lane], xb, wr[lane + 64]);
        #pragma unroll
        for (int off = 32; off; off >>= 1) acc += __shfl_xor(acc, off, 64);
        const float t = acc + bias[node];
        const float s = 1.0f - 2.0f * codes[(size_t)c * D + d];
        q *= 1.0f + __expf(-s * t);
    }
    if (lane == 0) out[p] = 1.0f / q;
}

extern "C" void kernel_launch(void* const* d_in, const int* in_sizes, int n_in,
                              void* d_out, int out_size, void* d_ws, size_t ws_size,
                              hipStream_t stream) {
    const float* x     = (const float*)d_in[0];
    const int*   tgt   = (const int*)  d_in[1];
    const float* W     = (const float*)d_in[2];
    const float* bias  = (const float*)d_in[3];
    const int*   paths = (const int*)  d_in[4];
    const float* codes = (const float*)d_in[5];
    float* out = (float*)d_out;

    const int N = in_sizes[3];            // total_nodes = nb_classes - 1
    const int C = N + 1;                  // nb_classes
    const int I = in_sizes[2] / N;        // input dim (512)
    const int B = in_sizes[0] / I;        // batch (1024)
    const int R = in_sizes[1] / B;        // requests (8)
    const int D = in_sizes[4] / C;        // max path depth

    const int npairs = B * R;

    const size_t y_bytes  = (size_t)TOPM * B * sizeof(float);
    const size_t wh_bytes = (size_t)TOPM * 512 * sizeof(_Float16);
    const size_t xh_bytes = (size_t)B * 512 * sizeof(_Float16);
    const size_t ws_need  = y_bytes + wh_bytes + xh_bytes;

    if (D == 16 && I == 512 && (B % 64) == 0 && (npairs % 4) == 0 &&
        N > TOPM + 64 && ws_size >= ws_need) {
        float*     Y  = (float*)d_ws;
        _Float16*  Wh = (_Float16*)((char*)d_ws + y_bytes);
        _Float16*  xh = (_Float16*)((char*)d_ws + y_bytes + wh_bytes);
        const int tb = N - TOPM;

        const int n0   = TOPM * 512 / 4;
        const int ntot = n0 + B * 512 / 4;
        conv_f16<<<(ntot + 255) / 256, 256, 0, stream>>>(W + (size_t)tb * 512, x, Wh, xh, n0, ntot);
        top_gemm<<<(TOPM / 128) * (B / 64), 256, 0, stream>>>(Wh, xh, Y, B);
        huff_combine<<<npairs / 4, 256, 0, stream>>>(x, tgt, W, bias, paths, codes,
                                                     Y, out, R, N, B);
    } else {
        const int grid = (npairs + 3) / 4;
        huff_kernel_gen<<<grid, 256, 0, stream>>>(x, tgt, W, bias, paths, codes,
                                                  out, R, I, D, npairs);
    }
}